// Round 21
// baseline (52.630 us; speedup 1.0000x reference)
//
#include <hip/hip_runtime.h>

typedef _Float16 f16;
typedef f16 h8 __attribute__((ext_vector_type(8)));
typedef float f32x4 __attribute__((ext_vector_type(4)));
typedef unsigned int uint;
typedef unsigned char uchar;

#define BM 32
#define KS_E 284         // k-blocks of 32 (283 real + 1 zero pad), k = 904*c + p
#define CSTR 920         // color row stride bytes

// LDS strides (halves / floats)
#define SH 136
#define SAZ 232          // [y(128) z(64) gf(16) zeropad(16)] + 8
#define SLOG 68

// ws layout: fp8 encoder B fragments [nt][ks][512B], then small weights (f16)
#define N_W1B (8*KS_E*512)   // bytes: 1,163,264
#define NCHUNK (8*KS_E*64)   // 8B chunks: 145,408
#define OW2   0
#define OWY   16384
#define OWZ   32768
#define ORZ1  40960
#define ORZ2  55296
#define ORY1  59392
#define ORY2  73728
#define OS1   81920
#define OS2   90112
#define N_SMH 94208

__device__ __forceinline__ float geluf(float x){
  return 0.5f * x * (1.0f + erff(x * 0.70710678118654752f));
}

#define MFMA16(a,b,c) __builtin_amdgcn_mfma_f32_16x16x32_f16(a, b, c, 0, 0, 0)

__device__ __forceinline__ f32x4 mfma8(uint2 a, uint2 b, f32x4 c){
  union { uint2 u; long long l; } ua, ub;
  ua.u = a; ub.u = b;
  return __builtin_amdgcn_mfma_f32_16x16x32_fp8_fp8(ua.l, ub.l, c, 0, 0, 0);
}

// one 16x16 C tile over K = nks*32; A from LDS (k = (lane>>4)*8+e), B prep-packed (same k-map)
__device__ __forceinline__ f32x4 mfma_tile(const f16* __restrict__ act, int strideH,
                                           const f16* __restrict__ Wbase,
                                           int nks, f32x4 acc, int lane){
  #pragma unroll
  for (int ks = 0; ks < nks; ++ks){
    h8 a = *(const h8*)(act + (lane&15)*strideH + ks*32 + (lane>>4)*8);
    h8 b = *(const h8*)(Wbase + ks*512 + lane*8);
    acc = MFMA16(a, b, acc);
  }
  return acc;
}

__device__ __forceinline__ f32x4 cinit(const float* __restrict__ bias, int Nb, int lane){
  float v = bias[Nb + (lane&15)];
  f32x4 c; c[0]=v; c[1]=v; c[2]=v; c[3]=v;
  return c;
}

// C layout (HW-verified): col = lane&15, row = ro + (lane>>4)*4 + reg
__device__ __forceinline__ void storeC16(f16* __restrict__ dst, int stride, int ro, int Nb,
                                         f32x4 c, int lane, bool dogelu){
  int col = Nb + (lane&15);
  int r0  = ro + (lane>>4)*4;
  #pragma unroll
  for (int r = 0; r < 4; ++r){
    float v = c[r];
    if (dogelu) v = geluf(v);
    dst[(r0+r)*stride + col] = (f16)v;
  }
}

// ---------------- prep (r20, verified) ----------------
// seg A (chunked): one thread per 8B fragment chunk; coalesced reads, one 8B store.
// seg B: small weights -> f16 MFMA fragment order
__global__ void prep_kernel(const float* __restrict__ w1,
  const float* __restrict__ w2, const float* __restrict__ wy, const float* __restrict__ wz,
  const float* __restrict__ rz1, const float* __restrict__ rz2,
  const float* __restrict__ ry1, const float* __restrict__ ry2,
  const float* __restrict__ sel1, const float* __restrict__ sel2, f16* __restrict__ ws)
{
  int idx = blockIdx.x * 256 + threadIdx.x;
  uchar* w8 = (uchar*)ws;
  if (idx < NCHUNK){
    int lane   = idx & 63;
    int fragid = idx >> 6;
    int nt = fragid / KS_E;
    int ks = fragid - nt*KS_E;
    int k0 = ks*32 + ((lane >> 4) << 3);
    int n  = nt*16 + (lane & 15);
    int c  = k0 / 904;
    int p0 = k0 - 904*c;
    uint lo = 0, hi = 0;
    if (c < 10){
      const float* src = w1 + (size_t)(p0*10 + c)*128 + n;   // p-stride = 1280 floats
      float v[8];
      #pragma unroll
      for (int e = 0; e < 8; ++e)
        v[e] = (p0 + e < 900) ? src[(size_t)e*1280] : 0.f;
      lo = (uint)__builtin_amdgcn_cvt_pk_fp8_f32(v[0], v[1], 0, false);
      lo = (uint)__builtin_amdgcn_cvt_pk_fp8_f32(v[2], v[3], (int)lo, true);
      hi = (uint)__builtin_amdgcn_cvt_pk_fp8_f32(v[4], v[5], 0, false);
      hi = (uint)__builtin_amdgcn_cvt_pk_fp8_f32(v[6], v[7], (int)hi, true);
    }
    uint2 pk; pk.x = lo; pk.y = hi;
    *(uint2*)(w8 + ((size_t)fragid << 9) + (lane << 3)) = pk;
    return;
  }
  int r = idx - NCHUNK;
  if (r >= N_SMH) return;
  f16* smw = (f16*)(w8 + N_W1B);
  const float* src; int Ksrc, N, KS, off, perm = 0;
  if      (r < OWY) { src=w2;   Ksrc=128; N=128; KS=4; off=OW2; }
  else if (r < OWZ) { src=wy;   Ksrc=128; N=128; KS=4; off=OWY; }
  else if (r < ORZ1){ src=wz;   Ksrc=128; N=64;  KS=4; off=OWZ; }
  else if (r < ORZ2){ src=rz1;  Ksrc=208; N=64;  KS=7; off=ORZ1; }
  else if (r < ORY1){ src=rz2;  Ksrc=64;  N=64;  KS=2; off=ORZ2; }
  else if (r < ORY2){ src=ry1;  Ksrc=208; N=64;  KS=7; off=ORY1; perm=1; }
  else if (r < OS1) { src=ry2;  Ksrc=64;  N=128; KS=2; off=ORY2; }
  else if (r < OS2) { src=sel1; Ksrc=128; N=64;  KS=4; off=OS1; }
  else              { src=sel2; Ksrc=64;  N=64;  KS=2; off=OS2; }
  int l    = r - off;
  int e    = l & 7;
  int lane = (l >> 3) & 63;
  int frag = l >> 9;
  int kst  = frag % KS;
  int nt   = frag / KS;
  int k    = kst*32 + (lane>>4)*8 + e;
  int o    = nt*16 + (lane&15);
  float v = 0.f;
  if (perm){
    int sr = (k < 128) ? 64 + k : (k < 192) ? k - 128 : (k < 208) ? k : -1;
    if (sr >= 0) v = src[sr*N + o];
  } else if (k < Ksrc) v = src[k*N + o];
  smw[r] = (f16)v;
}

// ---------------- encoder kernel (r13, verified 4x): h = gelu(onehot @ w1 + b1) ----------------
// fp8 path: A mask bytes 0x10 = 2^-5 in e4m3fn, compensated by x32 at epilogue.
extern "C" __global__ __launch_bounds__(512, 1) void enc_kernel(
  const int* __restrict__ grd, const float* __restrict__ b1,
  const f16* __restrict__ ws, f16* hbuf)
{
  __shared__ __align__(16) char colL[32*CSTR];

  const int t  = threadIdx.x;
  const int s0 = blockIdx.x * BM;
  const int lane = t & 63;
  const int w    = t >> 6;        // N-tile 0..7

  // pack colors to u8 rows
  {
    const uint4* gv = (const uint4*)(grd + (size_t)s0 * 900);
    #pragma unroll
    for (int it = 0; it < 15; ++it){
      int idx4 = it*512 + t;
      if (idx4 < 7200){
        uint4 v = gv[idx4];
        uint pk = (v.x & 255u) | ((v.y & 255u) << 8) | ((v.z & 255u) << 16) | ((v.w & 255u) << 24);
        uint s  = (uint)(idx4 * 9321u) >> 21;   // idx4 / 225
        uint p4 = (uint)idx4 - s * 225u;
        *(uint*)(colL + s*CSTR + p4*4) = pk;
      }
    }
  }
  __syncthreads();

  const char* colRowA = colL + (lane & 15) * CSTR;
  const char* colRowB = colRowA + 16 * CSTR;
  const char* Wp = (const char*)ws + (size_t)(w * KS_E) * 512 + lane*8;

  f32x4 acc0 = {0.f,0.f,0.f,0.f};
  f32x4 acc1 = {0.f,0.f,0.f,0.f};

  uint2 q0 = *(const uint2*)(Wp);
  uint2 q1 = *(const uint2*)(Wp + 512);
  uint2 q2 = *(const uint2*)(Wp + 1024);
  uint2 q3 = *(const uint2*)(Wp + 1536);
  uint k0 = (uint)((lane >> 4) * 8);

#define ESTEP(Q, PFIDX) { \
    uint q = k0 >> 3; \
    uint c = (q * 2320u) >> 18; \
    uint p0 = (q - 113u * c) << 3; \
    uint2 wvA = *(const uint2*)(colRowA + p0); \
    uint2 wvB = *(const uint2*)(colRowB + p0); \
    uint cc4 = c * 0x01010101u; \
    uint2 a0, a1; \
    a0.x = (0x10101010u - (wvA.x ^ cc4)) & 0x10101010u; \
    a0.y = (0x10101010u - (wvA.y ^ cc4)) & 0x10101010u; \
    a1.x = (0x10101010u - (wvB.x ^ cc4)) & 0x10101010u; \
    a1.y = (0x10101010u - (wvB.y ^ cc4)) & 0x10101010u; \
    acc0 = mfma8(a0, Q, acc0); \
    acc1 = mfma8(a1, Q, acc1); \
    Q = *(const uint2*)(Wp + (size_t)(PFIDX)*512); \
    k0 += 32; }
#define ETAIL(Q) { \
    uint q = k0 >> 3; \
    uint c = (q * 2320u) >> 18; \
    uint p0 = (q - 113u * c) << 3; \
    uint2 wvA = *(const uint2*)(colRowA + p0); \
    uint2 wvB = *(const uint2*)(colRowB + p0); \
    uint cc4 = c * 0x01010101u; \
    uint2 a0, a1; \
    a0.x = (0x10101010u - (wvA.x ^ cc4)) & 0x10101010u; \
    a0.y = (0x10101010u - (wvA.y ^ cc4)) & 0x10101010u; \
    a1.x = (0x10101010u - (wvB.x ^ cc4)) & 0x10101010u; \
    a1.y = (0x10101010u - (wvB.y ^ cc4)) & 0x10101010u; \
    acc0 = mfma8(a0, Q, acc0); \
    acc1 = mfma8(a1, Q, acc1); \
    k0 += 32; }

  #pragma unroll 2
  for (int it = 0; it < 70; ++it){
    ESTEP(q0, it*4 + 4)
    ESTEP(q1, it*4 + 5)
    ESTEP(q2, it*4 + 6)
    ESTEP(q3, it*4 + 7)
  }
  ETAIL(q0) ETAIL(q1) ETAIL(q2) ETAIL(q3)
#undef ESTEP
#undef ETAIL

  { // epilogue: x32 fp8 compensation + bias + gelu -> hbuf row-major [8192][128]
    int col = w*16 + (lane & 15);
    float bb = b1[col];
    int r0 = (lane >> 4) * 4;
    #pragma unroll
    for (int r = 0; r < 4; ++r){
      hbuf[(size_t)(s0 + r0 + r)*128 + col]      = (f16)geluf(acc0[r]*32.0f + bb);
      hbuf[(size_t)(s0 + 16 + r0 + r)*128 + col] = (f16)geluf(acc1[r]*32.0f + bb);
    }
  }
}

// ---------------- phases kernel: 32 samples/WG, 512 threads, waves (st, ns) ----------------
// r5/r6-proven phase structure as a standalone kernel: halves WG count (weight L2
// traffic /2) and doubles waves/CU (8 -> 16) to hide barrier-separated phase latency.
extern "C" __global__ __launch_bounds__(512, 2) void phases_kernel(
  const float* __restrict__ gfeat, const float* __restrict__ gum,
  const float* __restrict__ b2, const float* __restrict__ by, const float* __restrict__ bz,
  const float* __restrict__ rzb1, const float* __restrict__ rzb2,
  const float* __restrict__ ryb1, const float* __restrict__ ryb2,
  const float* __restrict__ sb1, const float* __restrict__ sb2,
  const f16* __restrict__ ws, const f16* hbuf, float* out)
{
  __shared__ __align__(16) f16 Hb[32*SH];
  __shared__ __align__(16) f16 Bb[32*SH];
  __shared__ __align__(16) f16 Az[32*SAZ];
  __shared__ __align__(16) float Lb[32*SLOG];

  const int t  = threadIdx.x;
  const int s0 = blockIdx.x * 32;
  const int lane  = t & 63;
  const int w     = t >> 6;        // 0..7
  const int st    = w & 1;         // sample-half
  const int ns    = w >> 1;        // N-slice 0..3
  const int slane = t >> 4;        // 0..31
  const int flane = t & 15;

  // stage h (one h8 per thread, coalesced), gf, zero K-pad
  {
    h8 hv = *(const h8*)(hbuf + (size_t)s0*128 + t*8);
    *(h8*)(Hb + (t>>4)*SH + (t&15)*8) = hv;
    Az[slane*SAZ + 192 + flane] = (f16)gfeat[(size_t)(s0 + slane)*16 + flane];
    Az[slane*SAZ + 208 + flane] = (f16)0.f;
  }
  __syncthreads();

  const f16* SMW = (const f16*)((const char*)ws + N_W1B);
  const f16* actH = Hb + st*16*SH;
  const f16* actB = Bb + st*16*SH;
  const f16* actA = Az + st*16*SAZ;

  // enc L2: h2 = gelu(h @ w2 + b2)
  {
    f32x4 c0 = cinit(b2, ns*32,      lane);
    f32x4 c1 = cinit(b2, ns*32 + 16, lane);
    c0 = mfma_tile(actH, SH, SMW + OW2 + (ns*2+0)*4*512, 4, c0, lane);
    c1 = mfma_tile(actH, SH, SMW + OW2 + (ns*2+1)*4*512, 4, c1, lane);
    storeC16(Bb, SH, st*16, ns*32,      c0, lane, true);
    storeC16(Bb, SH, st*16, ns*32 + 16, c1, lane, true);
  }
  __syncthreads();

  // heads: y = h2@wy+by ; z = h2@wz+bz
  {
    f32x4 y0 = cinit(by, ns*32,      lane);
    f32x4 y1 = cinit(by, ns*32 + 16, lane);
    f32x4 z0 = cinit(bz, ns*16,      lane);
    y0 = mfma_tile(actB, SH, SMW + OWY + (ns*2+0)*4*512, 4, y0, lane);
    y1 = mfma_tile(actB, SH, SMW + OWY + (ns*2+1)*4*512, 4, y1, lane);
    z0 = mfma_tile(actB, SH, SMW + OWZ + ns*4*512,       4, z0, lane);
    storeC16(Az, SAZ, st*16, ns*32,       y0, lane, false);
    storeC16(Az, SAZ, st*16, ns*32 + 16,  y1, lane, false);
    storeC16(Az, SAZ, st*16, 128 + ns*16, z0, lane, false);
  }
  __syncthreads();

  // 3 refinement cycles (weights from L2-hot global)
  #pragma unroll 1
  for (int cyc = 0; cyc < 3; ++cyc){
    { // hid = gelu([y,z,gf] @ rz1 + rzb1)   K=224
      f32x4 h0 = cinit(rzb1, ns*16, lane);
      h0 = mfma_tile(actA, SAZ, SMW + ORZ1 + ns*7*512, 7, h0, lane);
      storeC16(Bb, SH, st*16, ns*16, h0, lane, true);
    }
    __syncthreads();
    { // z = hid @ rz2 + rzb2   K=64
      f32x4 z = cinit(rzb2, ns*16, lane);
      z = mfma_tile(actB, SH, SMW + ORZ2 + ns*2*512, 2, z, lane);
      storeC16(Az, SAZ, st*16, 128 + ns*16, z, lane, false);
    }
    __syncthreads();
    { // hid = gelu([z,y,gf] @ ry1 + ryb1)   K=224 (perm-packed)
      f32x4 h1 = cinit(ryb1, ns*16, lane);
      h1 = mfma_tile(actA, SAZ, SMW + ORY1 + ns*7*512, 7, h1, lane);
      storeC16(Bb, SH, st*16, ns*16, h1, lane, true);
    }
    __syncthreads();
    { // y = hid @ ry2 + ryb2   K=64, N=128
      f32x4 y0 = cinit(ryb2, ns*32,      lane);
      f32x4 y1 = cinit(ryb2, ns*32 + 16, lane);
      y0 = mfma_tile(actB, SH, SMW + ORY2 + (ns*2+0)*2*512, 2, y0, lane);
      y1 = mfma_tile(actB, SH, SMW + ORY2 + (ns*2+1)*2*512, 2, y1, lane);
      storeC16(Az, SAZ, st*16, ns*32,      y0, lane, false);
      storeC16(Az, SAZ, st*16, ns*32 + 16, y1, lane, false);
    }
    __syncthreads();
  }

  // selector
  {
    f32x4 s1 = cinit(sb1, ns*16, lane);
    s1 = mfma_tile(actA, SAZ, SMW + OS1 + ns*4*512, 4, s1, lane);
    storeC16(Bb, SH, st*16, ns*16, s1, lane, true);
  }
  __syncthreads();
  {
    f32x4 lg = cinit(sb2, ns*16, lane);
    lg = mfma_tile(actB, SH, SMW + OS2 + ns*2*512, 2, lg, lane);
    int col = ns*16 + (lane & 15);
    int r0  = st*16 + (lane >> 4) * 4;
    #pragma unroll
    for (int rr = 0; rr < 4; ++rr)
      Lb[(r0+rr)*SLOG + col] = lg[rr] + gum[(size_t)(s0 + r0 + rr)*64 + col];
  }
  __syncthreads();

  // softmax (16 threads/sample, redundant row reduce); out overwrites this WG's hbuf rows
  {
    const float* row = Lb + slane*SLOG;
    float m = -3.0e38f;
    #pragma unroll
    for (int k4 = 0; k4 < 16; ++k4){
      float4 v = *(const float4*)(row + k4*4);
      m = fmaxf(m, fmaxf(fmaxf(v.x,v.y), fmaxf(v.z,v.w)));
    }
    float ssum = 0.f;
    #pragma unroll
    for (int k4 = 0; k4 < 16; ++k4){
      float4 v = *(const float4*)(row + k4*4);
      ssum += __expf(v.x-m)+__expf(v.y-m)+__expf(v.z-m)+__expf(v.w-m);
    }
    float inv = 1.0f / ssum;
    const size_t gsamp = (size_t)(s0 + slane);
    #pragma unroll
    for (int j = 0; j < 4; ++j){
      int o = flane + 16*j;
      out[gsamp*64 + o] = __expf(row[o]-m) * inv;
    }
  }
}

extern "C" void kernel_launch(void* const* d_in, const int* in_sizes, int n_in,
                              void* d_out, int out_size, void* d_ws, size_t ws_size,
                              hipStream_t stream) {
  const int*   grd   = (const int*)d_in[0];
  const float* gfeat = (const float*)d_in[1];
  const float* gum   = (const float*)d_in[2];
  const float* w1    = (const float*)d_in[3];
  const float* b1    = (const float*)d_in[4];
  const float* w2    = (const float*)d_in[5];
  const float* b2    = (const float*)d_in[6];
  const float* wy    = (const float*)d_in[7];
  const float* byb   = (const float*)d_in[8];
  const float* wz    = (const float*)d_in[9];
  const float* bz    = (const float*)d_in[10];
  const float* rz1   = (const float*)d_in[11];
  const float* rzb1  = (const float*)d_in[12];
  const float* rz2   = (const float*)d_in[13];
  const float* rzb2  = (const float*)d_in[14];
  const float* ry1   = (const float*)d_in[15];
  const float* ryb1  = (const float*)d_in[16];
  const float* ry2   = (const float*)d_in[17];
  const float* ryb2  = (const float*)d_in[18];
  const float* sel1  = (const float*)d_in[19];
  const float* sb1   = (const float*)d_in[20];
  const float* sel2  = (const float*)d_in[21];
  const float* sb2   = (const float*)d_in[22];

  f16* ws = (f16*)d_ws;
  // h buffer lives in d_out: sample i's h (128 f16 = 256B) occupies the same
  // 256B as its final output (64 f32); each WG reads its own rows before
  // overwriting them, so there is no cross-WG hazard.
  f16* hbuf = (f16*)d_out;
  float* outp = (float*)d_out;

  const int prep_total = NCHUNK + N_SMH;   // 239,616 = 936*256
  prep_kernel<<<prep_total/256, 256, 0, stream>>>(
      w1, w2, wy, wz, rz1, rz2, ry1, ry2, sel1, sel2, ws);

  enc_kernel<<<8192/BM, 512, 0, stream>>>(grd, b1, ws, hbuf);

  phases_kernel<<<8192/32, 512, 0, stream>>>(
      gfeat, gum, b2, byb, bz, rzb1, rzb2, ryb1, ryb2, sb1, sb2, ws, hbuf, outp);
}

// Round 22
// 51.857 us; speedup vs baseline: 1.0149x; 1.0149x over previous
//
#include <hip/hip_runtime.h>

typedef _Float16 f16;
typedef f16 h8 __attribute__((ext_vector_type(8)));
typedef float f32x4 __attribute__((ext_vector_type(4)));
typedef unsigned int uint;
typedef unsigned char uchar;

#define BM 32
#define KS_E 284         // k-blocks of 32 (283 real + 1 zero pad), k = 904*c + p
#define CSTR 920         // color row stride bytes

// LDS strides (halves / floats)
#define SH 136
#define SAZ 232          // [y(128) z(64) gf(16) zeropad(16)] + 8
#define SLOG 68

// ws layout: fp8 encoder B fragments [nt][ks][512B], then small weights (f16)
#define N_W1B (8*KS_E*512)   // bytes: 1,163,264
#define NCHUNK (8*KS_E*64)   // 8B chunks: 145,408
#define OW2   0
#define OWY   16384
#define OWZ   32768
#define ORZ1  40960
#define ORZ2  55296
#define ORY1  59392
#define ORY2  73728
#define OS1   81920
#define OS2   90112
#define N_SMH 94208

__device__ __forceinline__ float geluf(float x){
  return 0.5f * x * (1.0f + erff(x * 0.70710678118654752f));
}

#define MFMA16(a,b,c) __builtin_amdgcn_mfma_f32_16x16x32_f16(a, b, c, 0, 0, 0)

__device__ __forceinline__ f32x4 mfma8(uint2 a, uint2 b, f32x4 c){
  union { uint2 u; long long l; } ua, ub;
  ua.u = a; ub.u = b;
  return __builtin_amdgcn_mfma_f32_16x16x32_fp8_fp8(ua.l, ub.l, c, 0, 0, 0);
}

// one 16x16 C tile over K = nks*32; A from LDS (k = (lane>>4)*8+e), B prep-packed (same k-map)
__device__ __forceinline__ f32x4 mfma_tile(const f16* __restrict__ act, int strideH,
                                           const f16* __restrict__ Wbase,
                                           int nks, f32x4 acc, int lane){
  #pragma unroll
  for (int ks = 0; ks < nks; ++ks){
    h8 a = *(const h8*)(act + (lane&15)*strideH + ks*32 + (lane>>4)*8);
    h8 b = *(const h8*)(Wbase + ks*512 + lane*8);
    acc = MFMA16(a, b, acc);
  }
  return acc;
}

__device__ __forceinline__ f32x4 cinit(const float* __restrict__ bias, int Nb, int lane){
  float v = bias[Nb + (lane&15)];
  f32x4 c; c[0]=v; c[1]=v; c[2]=v; c[3]=v;
  return c;
}

// C layout (HW-verified): col = lane&15, row = (lane>>4)*4 + reg
__device__ __forceinline__ void storeC16(f16* __restrict__ dst, int stride, int Nb,
                                         f32x4 c, int lane, bool dogelu){
  int col = Nb + (lane&15);
  int r0  = (lane>>4)*4;
  #pragma unroll
  for (int r = 0; r < 4; ++r){
    float v = c[r];
    if (dogelu) v = geluf(v);
    dst[(r0+r)*stride + col] = (f16)v;
  }
}

// ---------------- prep (r20, verified) ----------------
// seg A (chunked): one thread per 8B fragment chunk. Chunk (nt,ks,lane) covers
//   k = ks*32 + (lane>>4)*8 + e (e=0..7), n = nt*16 + (lane&15); k = 904*c + p.
//   904 % 8 == 0 -> c uniform per chunk; coalesced reads, one 8B coalesced store.
// seg B: small weights -> f16 MFMA fragment order
__global__ void prep_kernel(const float* __restrict__ w1,
  const float* __restrict__ w2, const float* __restrict__ wy, const float* __restrict__ wz,
  const float* __restrict__ rz1, const float* __restrict__ rz2,
  const float* __restrict__ ry1, const float* __restrict__ ry2,
  const float* __restrict__ sel1, const float* __restrict__ sel2, f16* __restrict__ ws)
{
  int idx = blockIdx.x * 256 + threadIdx.x;
  uchar* w8 = (uchar*)ws;
  if (idx < NCHUNK){
    int lane   = idx & 63;
    int fragid = idx >> 6;
    int nt = fragid / KS_E;
    int ks = fragid - nt*KS_E;
    int k0 = ks*32 + ((lane >> 4) << 3);
    int n  = nt*16 + (lane & 15);
    int c  = k0 / 904;
    int p0 = k0 - 904*c;
    uint lo = 0, hi = 0;
    if (c < 10){
      const float* src = w1 + (size_t)(p0*10 + c)*128 + n;   // p-stride = 1280 floats
      float v[8];
      #pragma unroll
      for (int e = 0; e < 8; ++e)
        v[e] = (p0 + e < 900) ? src[(size_t)e*1280] : 0.f;
      lo = (uint)__builtin_amdgcn_cvt_pk_fp8_f32(v[0], v[1], 0, false);
      lo = (uint)__builtin_amdgcn_cvt_pk_fp8_f32(v[2], v[3], (int)lo, true);
      hi = (uint)__builtin_amdgcn_cvt_pk_fp8_f32(v[4], v[5], 0, false);
      hi = (uint)__builtin_amdgcn_cvt_pk_fp8_f32(v[6], v[7], (int)hi, true);
    }
    uint2 pk; pk.x = lo; pk.y = hi;
    *(uint2*)(w8 + ((size_t)fragid << 9) + (lane << 3)) = pk;
    return;
  }
  int r = idx - NCHUNK;
  if (r >= N_SMH) return;
  f16* smw = (f16*)(w8 + N_W1B);
  const float* src; int Ksrc, N, KS, off, perm = 0;
  if      (r < OWY) { src=w2;   Ksrc=128; N=128; KS=4; off=OW2; }
  else if (r < OWZ) { src=wy;   Ksrc=128; N=128; KS=4; off=OWY; }
  else if (r < ORZ1){ src=wz;   Ksrc=128; N=64;  KS=4; off=OWZ; }
  else if (r < ORZ2){ src=rz1;  Ksrc=208; N=64;  KS=7; off=ORZ1; }
  else if (r < ORY1){ src=rz2;  Ksrc=64;  N=64;  KS=2; off=ORZ2; }
  else if (r < ORY2){ src=ry1;  Ksrc=208; N=64;  KS=7; off=ORY1; perm=1; }
  else if (r < OS1) { src=ry2;  Ksrc=64;  N=128; KS=2; off=ORY2; }
  else if (r < OS2) { src=sel1; Ksrc=128; N=64;  KS=4; off=OS1; }
  else              { src=sel2; Ksrc=64;  N=64;  KS=2; off=OS2; }
  int l    = r - off;
  int e    = l & 7;
  int lane = (l >> 3) & 63;
  int frag = l >> 9;
  int kst  = frag % KS;
  int nt   = frag / KS;
  int k    = kst*32 + (lane>>4)*8 + e;
  int o    = nt*16 + (lane&15);
  float v = 0.f;
  if (perm){
    int sr = (k < 128) ? 64 + k : (k < 192) ? k - 128 : (k < 208) ? k : -1;
    if (sr >= 0) v = src[sr*N + o];
  } else if (k < Ksrc) v = src[k*N + o];
  smw[r] = (f16)v;
}

// ---------------- encoder kernel (r13, verified 4x): h = gelu(onehot @ w1 + b1) ----------------
// fp8 path: A mask bytes 0x10 = 2^-5 in e4m3fn, compensated by x32 at epilogue.
extern "C" __global__ __launch_bounds__(512, 1) void enc_kernel(
  const int* __restrict__ grd, const float* __restrict__ b1,
  const f16* __restrict__ ws, f16* hbuf)
{
  __shared__ __align__(16) char colL[32*CSTR];

  const int t  = threadIdx.x;
  const int s0 = blockIdx.x * BM;
  const int lane = t & 63;
  const int w    = t >> 6;        // N-tile 0..7

  // pack colors to u8 rows
  {
    const uint4* gv = (const uint4*)(grd + (size_t)s0 * 900);
    #pragma unroll
    for (int it = 0; it < 15; ++it){
      int idx4 = it*512 + t;
      if (idx4 < 7200){
        uint4 v = gv[idx4];
        uint pk = (v.x & 255u) | ((v.y & 255u) << 8) | ((v.z & 255u) << 16) | ((v.w & 255u) << 24);
        uint s  = (uint)(idx4 * 9321u) >> 21;   // idx4 / 225
        uint p4 = (uint)idx4 - s * 225u;
        *(uint*)(colL + s*CSTR + p4*4) = pk;
      }
    }
  }
  __syncthreads();

  const char* colRowA = colL + (lane & 15) * CSTR;
  const char* colRowB = colRowA + 16 * CSTR;
  const char* Wp = (const char*)ws + (size_t)(w * KS_E) * 512 + lane*8;

  f32x4 acc0 = {0.f,0.f,0.f,0.f};
  f32x4 acc1 = {0.f,0.f,0.f,0.f};

  uint2 q0 = *(const uint2*)(Wp);
  uint2 q1 = *(const uint2*)(Wp + 512);
  uint2 q2 = *(const uint2*)(Wp + 1024);
  uint2 q3 = *(const uint2*)(Wp + 1536);
  uint k0 = (uint)((lane >> 4) * 8);

#define ESTEP(Q, PFIDX) { \
    uint q = k0 >> 3; \
    uint c = (q * 2320u) >> 18; \
    uint p0 = (q - 113u * c) << 3; \
    uint2 wvA = *(const uint2*)(colRowA + p0); \
    uint2 wvB = *(const uint2*)(colRowB + p0); \
    uint cc4 = c * 0x01010101u; \
    uint2 a0, a1; \
    a0.x = (0x10101010u - (wvA.x ^ cc4)) & 0x10101010u; \
    a0.y = (0x10101010u - (wvA.y ^ cc4)) & 0x10101010u; \
    a1.x = (0x10101010u - (wvB.x ^ cc4)) & 0x10101010u; \
    a1.y = (0x10101010u - (wvB.y ^ cc4)) & 0x10101010u; \
    acc0 = mfma8(a0, Q, acc0); \
    acc1 = mfma8(a1, Q, acc1); \
    Q = *(const uint2*)(Wp + (size_t)(PFIDX)*512); \
    k0 += 32; }
#define ETAIL(Q) { \
    uint q = k0 >> 3; \
    uint c = (q * 2320u) >> 18; \
    uint p0 = (q - 113u * c) << 3; \
    uint2 wvA = *(const uint2*)(colRowA + p0); \
    uint2 wvB = *(const uint2*)(colRowB + p0); \
    uint cc4 = c * 0x01010101u; \
    uint2 a0, a1; \
    a0.x = (0x10101010u - (wvA.x ^ cc4)) & 0x10101010u; \
    a0.y = (0x10101010u - (wvA.y ^ cc4)) & 0x10101010u; \
    a1.x = (0x10101010u - (wvB.x ^ cc4)) & 0x10101010u; \
    a1.y = (0x10101010u - (wvB.y ^ cc4)) & 0x10101010u; \
    acc0 = mfma8(a0, Q, acc0); \
    acc1 = mfma8(a1, Q, acc1); \
    k0 += 32; }

  #pragma unroll 2
  for (int it = 0; it < 70; ++it){
    ESTEP(q0, it*4 + 4)
    ESTEP(q1, it*4 + 5)
    ESTEP(q2, it*4 + 6)
    ESTEP(q3, it*4 + 7)
  }
  ETAIL(q0) ETAIL(q1) ETAIL(q2) ETAIL(q3)
#undef ESTEP
#undef ETAIL

  { // epilogue: x32 fp8 compensation + bias + gelu -> hbuf row-major [8192][128]
    int col = w*16 + (lane & 15);
    float bb = b1[col];
    int r0 = (lane >> 4) * 4;
    #pragma unroll
    for (int r = 0; r < 4; ++r){
      hbuf[(size_t)(s0 + r0 + r)*128 + col]      = (f16)geluf(acc0[r]*32.0f + bb);
      hbuf[(size_t)(s0 + 16 + r0 + r)*128 + col] = (f16)geluf(acc1[r]*32.0f + bb);
    }
  }
}

// ---------------- phases kernel (r20, verified): 16 samples/WG, 256 threads ----------------
extern "C" __global__ __launch_bounds__(256, 2) void phases_kernel(
  const float* __restrict__ gfeat, const float* __restrict__ gum,
  const float* __restrict__ b2, const float* __restrict__ by, const float* __restrict__ bz,
  const float* __restrict__ rzb1, const float* __restrict__ rzb2,
  const float* __restrict__ ryb1, const float* __restrict__ ryb2,
  const float* __restrict__ sb1, const float* __restrict__ sb2,
  const f16* __restrict__ ws, const f16* hbuf, float* out)
{
  __shared__ __align__(16) f16 Hb[16*SH];
  __shared__ __align__(16) f16 Bb[16*SH];
  __shared__ __align__(16) f16 Az[16*SAZ];
  __shared__ __align__(16) float Lb[16*SLOG];

  const int t  = threadIdx.x;
  const int s0 = blockIdx.x * 16;
  const int lane  = t & 63;
  const int ns    = t >> 6;        // N-slice 0..3
  const int slane = t >> 4;        // sample 0..15
  const int flane = t & 15;

  // stage h (coalesced global read -> padded LDS), gf, zero K-pad
  {
    h8 hv = *(const h8*)(hbuf + (size_t)s0*128 + t*8);
    *(h8*)(Hb + (t>>4)*SH + (t&15)*8) = hv;
    Az[slane*SAZ + 192 + flane] = (f16)gfeat[(size_t)(s0 + slane)*16 + flane];
    Az[slane*SAZ + 208 + flane] = (f16)0.f;
  }
  __syncthreads();

  const f16* SMW = (const f16*)((const char*)ws + N_W1B);

  // enc L2: h2 = gelu(h @ w2 + b2)
  {
    f32x4 c0 = cinit(b2, ns*32,      lane);
    f32x4 c1 = cinit(b2, ns*32 + 16, lane);
    c0 = mfma_tile(Hb, SH, SMW + OW2 + (ns*2+0)*4*512, 4, c0, lane);
    c1 = mfma_tile(Hb, SH, SMW + OW2 + (ns*2+1)*4*512, 4, c1, lane);
    storeC16(Bb, SH, ns*32,      c0, lane, true);
    storeC16(Bb, SH, ns*32 + 16, c1, lane, true);
  }
  __syncthreads();

  // heads: y = h2@wy+by ; z = h2@wz+bz
  {
    f32x4 y0 = cinit(by, ns*32,      lane);
    f32x4 y1 = cinit(by, ns*32 + 16, lane);
    f32x4 z0 = cinit(bz, ns*16,      lane);
    y0 = mfma_tile(Bb, SH, SMW + OWY + (ns*2+0)*4*512, 4, y0, lane);
    y1 = mfma_tile(Bb, SH, SMW + OWY + (ns*2+1)*4*512, 4, y1, lane);
    z0 = mfma_tile(Bb, SH, SMW + OWZ + ns*4*512,       4, z0, lane);
    storeC16(Az, SAZ, ns*32,       y0, lane, false);
    storeC16(Az, SAZ, ns*32 + 16,  y1, lane, false);
    storeC16(Az, SAZ, 128 + ns*16, z0, lane, false);
  }
  __syncthreads();

  // 3 refinement cycles (weights from L2-hot global)
  #pragma unroll 1
  for (int cyc = 0; cyc < 3; ++cyc){
    { // hid = gelu([y,z,gf] @ rz1 + rzb1)   K=224
      f32x4 h0 = cinit(rzb1, ns*16, lane);
      h0 = mfma_tile(Az, SAZ, SMW + ORZ1 + ns*7*512, 7, h0, lane);
      storeC16(Bb, SH, ns*16, h0, lane, true);
    }
    __syncthreads();
    { // z = hid @ rz2 + rzb2   K=64
      f32x4 z = cinit(rzb2, ns*16, lane);
      z = mfma_tile(Bb, SH, SMW + ORZ2 + ns*2*512, 2, z, lane);
      storeC16(Az, SAZ, 128 + ns*16, z, lane, false);
    }
    __syncthreads();
    { // hid = gelu([z,y,gf] @ ry1 + ryb1)   K=224 (perm-packed)
      f32x4 h1 = cinit(ryb1, ns*16, lane);
      h1 = mfma_tile(Az, SAZ, SMW + ORY1 + ns*7*512, 7, h1, lane);
      storeC16(Bb, SH, ns*16, h1, lane, true);
    }
    __syncthreads();
    { // y = hid @ ry2 + ryb2   K=64, N=128
      f32x4 y0 = cinit(ryb2, ns*32,      lane);
      f32x4 y1 = cinit(ryb2, ns*32 + 16, lane);
      y0 = mfma_tile(Bb, SH, SMW + ORY2 + (ns*2+0)*2*512, 2, y0, lane);
      y1 = mfma_tile(Bb, SH, SMW + ORY2 + (ns*2+1)*2*512, 2, y1, lane);
      storeC16(Az, SAZ, ns*32,      y0, lane, false);
      storeC16(Az, SAZ, ns*32 + 16, y1, lane, false);
    }
    __syncthreads();
  }

  // selector
  {
    f32x4 s1 = cinit(sb1, ns*16, lane);
    s1 = mfma_tile(Az, SAZ, SMW + OS1 + ns*4*512, 4, s1, lane);
    storeC16(Bb, SH, ns*16, s1, lane, true);
  }
  __syncthreads();
  {
    f32x4 lg = cinit(sb2, ns*16, lane);
    lg = mfma_tile(Bb, SH, SMW + OS2 + ns*2*512, 2, lg, lane);
    int col = ns*16 + (lane & 15);
    int r0  = (lane >> 4) * 4;
    #pragma unroll
    for (int rr = 0; rr < 4; ++rr)
      Lb[(r0+rr)*SLOG + col] = lg[rr] + gum[(size_t)(s0 + r0 + rr)*64 + col];
  }
  __syncthreads();

  // softmax (16 threads/sample, redundant row reduce); out overwrites this WG's hbuf rows
  {
    const float* row = Lb + slane*SLOG;
    float m = -3.0e38f;
    #pragma unroll
    for (int k4 = 0; k4 < 16; ++k4){
      float4 v = *(const float4*)(row + k4*4);
      m = fmaxf(m, fmaxf(fmaxf(v.x,v.y), fmaxf(v.z,v.w)));
    }
    float ssum = 0.f;
    #pragma unroll
    for (int k4 = 0; k4 < 16; ++k4){
      float4 v = *(const float4*)(row + k4*4);
      ssum += __expf(v.x-m)+__expf(v.y-m)+__expf(v.z-m)+__expf(v.w-m);
    }
    float inv = 1.0f / ssum;
    const size_t gsamp = (size_t)(s0 + slane);
    #pragma unroll
    for (int j = 0; j < 4; ++j){
      int o = flane + 16*j;
      out[gsamp*64 + o] = __expf(row[o]-m) * inv;
    }
  }
}

extern "C" void kernel_launch(void* const* d_in, const int* in_sizes, int n_in,
                              void* d_out, int out_size, void* d_ws, size_t ws_size,
                              hipStream_t stream) {
  const int*   grd   = (const int*)d_in[0];
  const float* gfeat = (const float*)d_in[1];
  const float* gum   = (const float*)d_in[2];
  const float* w1    = (const float*)d_in[3];
  const float* b1    = (const float*)d_in[4];
  const float* w2    = (const float*)d_in[5];
  const float* b2    = (const float*)d_in[6];
  const float* wy    = (const float*)d_in[7];
  const float* byb   = (const float*)d_in[8];
  const float* wz    = (const float*)d_in[9];
  const float* bz    = (const float*)d_in[10];
  const float* rz1   = (const float*)d_in[11];
  const float* rzb1  = (const float*)d_in[12];
  const float* rz2   = (const float*)d_in[13];
  const float* rzb2  = (const float*)d_in[14];
  const float* ry1   = (const float*)d_in[15];
  const float* ryb1  = (const float*)d_in[16];
  const float* ry2   = (const float*)d_in[17];
  const float* ryb2  = (const float*)d_in[18];
  const float* sel1  = (const float*)d_in[19];
  const float* sb1   = (const float*)d_in[20];
  const float* sel2  = (const float*)d_in[21];
  const float* sb2   = (const float*)d_in[22];

  f16* ws = (f16*)d_ws;
  // h buffer lives in d_out: sample i's h (128 f16 = 256B) occupies the same
  // 256B as its final output (64 f32); each WG reads its own rows before
  // overwriting them, so there is no cross-WG hazard.
  f16* hbuf = (f16*)d_out;
  float* outp = (float*)d_out;

  const int prep_total = NCHUNK + N_SMH;   // 239,616 = 936*256
  prep_kernel<<<prep_total/256, 256, 0, stream>>>(
      w1, w2, wy, wz, rz1, rz2, ry1, ry2, sel1, sel2, ws);

  enc_kernel<<<8192/BM, 512, 0, stream>>>(grd, b1, ws, hbuf);

  phases_kernel<<<8192/16, 256, 0, stream>>>(
      gfeat, gum, b2, byb, bz, rzb1, rzb2, ryb1, ryb2, sb1, sb2, ws, hbuf, outp);
}